// Round 5
// baseline (358.027 us; speedup 1.0000x reference)
//
#include <hip/hip_runtime.h>
#include <hip/hip_bf16.h>

// MaceEquivariantScorePredictionHead — MI355X (gfx950), fused persistent kernel
// with hand-rolled grid barrier (no cooperative API — round-4's coop launch
// silently failed, output never written).
//
// Algebra:
//  * s-path is dead code (output depends on v only).
//  * t = times @ W_time is rank-1 => v0 = times[n] * (x_v @ C1),
//    C1[v,o] = tp_norm * sum_u W_time[u]*W_tp1[u,v,o]  (fixed 128x128).
//  * m-planes independent through all GEMMs; couple only via per-channel ssq
//    => block = 192 rows of flattened (m*N+n) space; V tile lives in LDS
//    (48 KB) through TP + 3 layers + final dot; V never touches HBM.
//  * norm scale folded into next layer's W fragments; ssq via spread global
//    atomics + grid barrier.
// Grid: 512 blocks x 256 thr = exactly 2 blocks/CU (launch_bounds(256,2);
// LDS 57.6KB x 2 = 115KB <= 160KB; VGPR ~170 <= 256) -> all co-resident.

#define N_NODES 32768
#define NMf 98304.0f
#define NB 512
#define ROWS 192

typedef __bf16 bf16_t;
typedef __bf16 bf16x4 __attribute__((ext_vector_type(4)));
typedef __bf16 bf16x8 __attribute__((ext_vector_type(8)));
typedef float f32x4 __attribute__((ext_vector_type(4)));

#define TP_NORM    0.022097086912079608f  /* 1/sqrt(16*128) */
#define INV_SQRT_V 0.08838834764831845f   /* 1/sqrt(128) */
#define EPSV       1e-5f
#define SW(r) (((r) & 7) << 4)

static constexpr int    BSW_ELEMS = 128 * 128;               // bf16 per matrix
static constexpr size_t SSQ_OFF   = 4 * BSW_ELEMS * 2;       // bytes into ws
static constexpr size_t BAR_OFF   = SSQ_OFF + 3 * 1024 * 4;  // bar @ +0, gen @ +64

// sense-reversing grid barrier: one arrival per block, device-scope atomics.
__device__ __forceinline__ void gridbar(int* bar, int* gen) {
  __syncthreads();
  if (threadIdx.x == 0) {
    int g = __hip_atomic_load(gen, __ATOMIC_ACQUIRE, __HIP_MEMORY_SCOPE_AGENT);
    int a = __hip_atomic_fetch_add(bar, 1, __ATOMIC_ACQ_REL, __HIP_MEMORY_SCOPE_AGENT);
    if (a == NB - 1) {
      __hip_atomic_store(bar, 0, __ATOMIC_RELAXED, __HIP_MEMORY_SCOPE_AGENT);
      __hip_atomic_fetch_add(gen, 1, __ATOMIC_ACQ_REL, __HIP_MEMORY_SCOPE_AGENT);
    } else {
      while (__hip_atomic_load(gen, __ATOMIC_ACQUIRE, __HIP_MEMORY_SCOPE_AGENT) == g)
        __builtin_amdgcn_s_sleep(2);
    }
  }
  __syncthreads();
}

__global__ __launch_bounds__(256, 2) void k_fused(
    const float* __restrict__ feat, const float* __restrict__ times,
    const float* __restrict__ Wt, const float* __restrict__ Wtp1,
    const float* __restrict__ Wv, const float* __restrict__ gv,
    const float* __restrict__ Wr, float* __restrict__ out,
    bf16_t* __restrict__ bsw, float* __restrict__ ssqb, int* __restrict__ bar) {
  __shared__ char  Vt[ROWS * 256];   // [row][chan] bf16, XOR-swizzled (48 KB)
  __shared__ char  SG[16 * 256];     // TP staging chunk
  __shared__ float tl[ROWS];
  __shared__ float aw[128];
  __shared__ float red[4 * ROWS];

  int* gen = bar + 16;               // separate cacheline
  int b = blockIdx.x, t = threadIdx.x;
  int r0 = b * ROWS;                 // flattened row base, r = m*N + n

  // ---- P0: weight fragments into ws. frag: flat=((ot*4+ks)*64+lane)*8+j ;
  // k=ks*32+(lane>>4)*8+j ; o=ot*16+(lane&15)
  if (b < 64) {
    int k = 2 * b + (t >> 7), o = t & 127;
    float acc = 0.f;
#pragma unroll
    for (int u = 0; u < 16; ++u) acc += Wt[u] * Wtp1[(u * 128 + k) * 128 + o];
    int ks = k >> 5, hi = (k >> 3) & 3, j = k & 7;
    int l = hi * 16 + (o & 15), ot = o >> 4;
    bsw[((ot * 4 + ks) * 64 + l) * 8 + j] = (bf16_t)(acc * TP_NORM);
  } else if (b < 88) {
    int vid = (b - 64) * 256 + t;    // 0..6143
    int mat = 1 + (vid >> 11);
    int idx = vid & 2047;
    int l = idx & 63;
    int o = ((idx >> 8) << 4) + (l & 15);
    int kbase = ((idx >> 6) & 3) * 32 + (l >> 4) * 8;
    bf16x8 o8;
#pragma unroll
    for (int j = 0; j < 8; ++j)
      o8[j] = (bf16_t)(Wv[((mat - 1) * 128 + kbase + j) * 128 + o] * INV_SQRT_V);
    *(bf16x8*)(bsw + (size_t)mat * BSW_ELEMS + (size_t)idx * 8) = o8;
  }
  if (t < ROWS) tl[t] = times[(r0 + t) & (N_NODES - 1)];
  gridbar(bar, gen);

  int w = t >> 6, l = t & 63, lr = l & 15, lq = l >> 4;

  // ---- P1: TP GEMM into Vt. Chunked: 12 x 16 rows.
  {
    bf16x8 cf[2][4];
#pragma unroll
    for (int j = 0; j < 2; ++j)
#pragma unroll
      for (int ks = 0; ks < 4; ++ks)
        cf[j][ks] = *(const bf16x8*)(bsw + (((2 * w + j) * 4 + ks) * 64 + l) * 8);
    for (int c = 0; c < 12; ++c) {
      __syncthreads();
#pragma unroll
      for (int h = 0; h < 2; ++h) {
        int s = h * 256 + t;
        int row = s >> 5, q = s & 31;
        int r = r0 + c * 16 + row;
        int m = r >> 15, n = r & (N_NODES - 1);
        const float* p = feat + (size_t)n * 512 + 128 + q * 12;
        float4 x0 = *(const float4*)p;
        float4 x1 = *(const float4*)(p + 4);
        float4 x2 = *(const float4*)(p + 8);
        // plane-m elements at local positions 3i+m of the 12-float window
        float e0 = m == 0 ? x0.x : (m == 1 ? x0.y : x0.z);
        float e1 = m == 0 ? x0.w : (m == 1 ? x1.x : x1.y);
        float e2 = m == 0 ? x1.z : (m == 1 ? x1.w : x2.x);
        float e3 = m == 0 ? x2.y : (m == 1 ? x2.z : x2.w);
        bf16x4 b4 = {(bf16_t)e0, (bf16_t)e1, (bf16_t)e2, (bf16_t)e3};
        *(bf16x4*)(SG + row * 256 + ((q * 8) ^ SW(row))) = b4;
      }
      __syncthreads();
      f32x4 a2[2] = {{0.f,0.f,0.f,0.f},{0.f,0.f,0.f,0.f}};
#pragma unroll
      for (int ks = 0; ks < 4; ++ks) {
        bf16x8 xf = *(const bf16x8*)(SG + lr * 256 + ((ks * 64 + lq * 16) ^ SW(lr)));
        a2[0] = __builtin_amdgcn_mfma_f32_16x16x32_bf16(cf[0][ks], xf, a2[0], 0, 0, 0);
        a2[1] = __builtin_amdgcn_mfma_f32_16x16x32_bf16(cf[1][ks], xf, a2[1], 0, 0, 0);
      }
      int rl = c * 16 + lr;
      float tv = tl[rl];
#pragma unroll
      for (int j = 0; j < 2; ++j) {
        bf16x4 b4;
#pragma unroll
        for (int i = 0; i < 4; ++i) b4[i] = (bf16_t)(a2[j][i] * tv);
        *(bf16x4*)(Vt + rl * 256 + ((((2 * w + j) * 16 + lq * 4) * 2) ^ SW(rl))) = b4;
      }
    }
    __syncthreads();
  }

  // ---- P2..P4: three layer GEMMs in LDS; ssq via spread atomics + gridbar
  f32x4 acc[2][12];
  for (int li = 0; li < 3; ++li) {
    if (li >= 1) {
      if (t < 128) {
        float s = 0.f;
#pragma unroll
        for (int q = 0; q < 8; ++q) s += ssqb[(li - 1) * 1024 + q * 128 + t];
        aw[t] = gv[(li - 1) * 128 + t] * rsqrtf(s * (1.0f / NMf) + EPSV);
      }
      __syncthreads();
    }
    bf16x8 wf[2][4];
#pragma unroll
    for (int j = 0; j < 2; ++j)
#pragma unroll
      for (int ks = 0; ks < 4; ++ks) {
        bf16x8 rw = *(const bf16x8*)(bsw + (size_t)(1 + li) * BSW_ELEMS +
                                     (((2 * w + j) * 4 + ks) * 64 + l) * 8);
        if (li >= 1) {
#pragma unroll
          for (int e = 0; e < 8; ++e)
            rw[e] = (bf16_t)((float)rw[e] * aw[ks * 32 + lq * 8 + e]);
        }
        wf[j][ks] = rw;
      }
#pragma unroll
    for (int j = 0; j < 2; ++j)
#pragma unroll
      for (int g = 0; g < 12; ++g) acc[j][g] = (f32x4){0.f, 0.f, 0.f, 0.f};
#pragma unroll
    for (int g = 0; g < 12; ++g) {
      int row = g * 16 + lr;
#pragma unroll
      for (int ks = 0; ks < 4; ++ks) {
        bf16x8 xf = *(const bf16x8*)(Vt + row * 256 + ((ks * 64 + lq * 16) ^ SW(row)));
        acc[0][g] = __builtin_amdgcn_mfma_f32_16x16x32_bf16(wf[0][ks], xf, acc[0][g], 0, 0, 0);
        acc[1][g] = __builtin_amdgcn_mfma_f32_16x16x32_bf16(wf[1][ks], xf, acc[1][g], 0, 0, 0);
      }
    }
    // ssq partials: reduce over cols (lr), spread atomics by block
    f32x4 s2[2] = {{0.f,0.f,0.f,0.f},{0.f,0.f,0.f,0.f}};
#pragma unroll
    for (int j = 0; j < 2; ++j)
#pragma unroll
      for (int g = 0; g < 12; ++g) s2[j] += acc[j][g] * acc[j][g];
#pragma unroll
    for (int j = 0; j < 2; ++j)
#pragma unroll
      for (int i = 0; i < 4; ++i) {
        float v = s2[j][i];
        v += __shfl_xor(v, 1); v += __shfl_xor(v, 2);
        v += __shfl_xor(v, 4); v += __shfl_xor(v, 8);
        s2[j][i] = v;
      }
    if (lr == 0) {
#pragma unroll
      for (int j = 0; j < 2; ++j)
#pragma unroll
        for (int i = 0; i < 4; ++i)
          atomicAdd(ssqb + li * 1024 + (b & 7) * 128 + (2 * w + j) * 16 + lq * 4 + i,
                    s2[j][i]);
    }
    if (li < 2) {
      __syncthreads();   // all Vt reads done before in-place write
#pragma unroll
      for (int j = 0; j < 2; ++j)
#pragma unroll
        for (int g = 0; g < 12; ++g) {
          int row = g * 16 + lr;
          bf16x4 b4;
#pragma unroll
          for (int i = 0; i < 4; ++i) b4[i] = (bf16_t)(acc[j][g][i]);
          *(bf16x4*)(Vt + row * 256 + ((((2 * w + j) * 16 + lq * 4) * 2) ^ SW(row))) = b4;
        }
    }
    gridbar(bar, gen);
  }

  // ---- P5: final dot straight from layer-3 accumulators
  if (t < 128) {
    float s = 0.f;
#pragma unroll
    for (int q = 0; q < 8; ++q) s += ssqb[2 * 1024 + q * 128 + t];
    aw[t] = gv[2 * 128 + t] * rsqrtf(s * (1.0f / NMf) + EPSV) * Wr[t] * INV_SQRT_V;
  }
  __syncthreads();
  float part[12];
#pragma unroll
  for (int g = 0; g < 12; ++g) part[g] = 0.f;
#pragma unroll
  for (int j = 0; j < 2; ++j) {
    int ob = (2 * w + j) * 16 + lq * 4;
    float w0 = aw[ob], w1 = aw[ob + 1], w2 = aw[ob + 2], w3v = aw[ob + 3];
#pragma unroll
    for (int g = 0; g < 12; ++g)
      part[g] += acc[j][g][0] * w0 + acc[j][g][1] * w1 +
                 acc[j][g][2] * w2 + acc[j][g][3] * w3v;
  }
#pragma unroll
  for (int g = 0; g < 12; ++g) {
    part[g] += __shfl_xor(part[g], 16);
    part[g] += __shfl_xor(part[g], 32);
  }
  if (lq == 0) {
#pragma unroll
    for (int g = 0; g < 12; ++g) red[w * ROWS + g * 16 + lr] = part[g];
  }
  __syncthreads();
  if (t < ROWS) {
    float s = red[t] + red[ROWS + t] + red[2 * ROWS + t] + red[3 * ROWS + t];
    int r = r0 + t;
    out[(size_t)(r & (N_NODES - 1)) * 3 + (r >> 15)] = s;
  }
}

// ---------------------------------------------------------------- launch
extern "C" void kernel_launch(void* const* d_in, const int* in_sizes, int n_in,
                              void* d_out, int out_size, void* d_ws, size_t ws_size,
                              hipStream_t stream) {
  const float* feat  = (const float*)d_in[0];
  const float* times = (const float*)d_in[1];
  const float* Wt    = (const float*)d_in[2];
  const float* Wtp1  = (const float*)d_in[4];   // W_tp0/Ws/gamma_s/beta_s dead
  const float* Wv    = (const float*)d_in[6];
  const float* gv    = (const float*)d_in[9];
  const float* Wr    = (const float*)d_in[10];
  float* out = (float*)d_out;

  bf16_t* bsw  = (bf16_t*)d_ws;
  float*  ssqb = (float*)((char*)d_ws + SSQ_OFF);
  int*    bar  = (int*)((char*)d_ws + BAR_OFF);

  // zero ssq accumulators + barrier state (ws is poisoned before every launch)
  hipMemsetAsync(ssqb, 0, 3 * 1024 * sizeof(float) + 128, stream);
  k_fused<<<NB, 256, 0, stream>>>(feat, times, Wt, Wtp1, Wv, gv, Wr, out,
                                  bsw, ssqb, bar);
}

// Round 10
// 146.869 us; speedup vs baseline: 2.4377x; 2.4377x over previous
//
#include <hip/hip_runtime.h>
#include <hip/hip_bf16.h>

// MaceEquivariantScorePredictionHead — MI355X (gfx950), fused persistent kernel.
// Round-7 (resubmit x3): fixes round-6's staging bug (only half the x_v span
// was staged: 48 float4/row instead of 96 => TP read uninitialized LDS,
// absmax 4.7). Keeps round-6's relaxed-atomic tree grid-barrier (round-5's
// ACQUIRE-spin barrier caused an L2-invalidate storm => 95% idle) and
// plane-triple blocks.
//
// Algebra:
//  * s-path is dead code (output depends on v only).
//  * t = times @ W_time is rank-1 => v0 = times[n] * (x_v @ C1),
//    C1[v,o] = tp_norm * sum_u W_time[u]*W_tp1[u,v,o]  (fixed 128x128).
//  * block = 64 nodes x 3 planes (192 rows); V tile resident in LDS (48 KB)
//    through TP + 3 layers + final dot; V never touches HBM.
//  * per-channel ssq via spread device atomics; barrier; norm scale folded
//    into the next layer's W fragments; final dot from accumulators.

#define N_NODES 32768
#define NMf 98304.0f
#define NB 512           // blocks; 16 per group, 32 groups
#define NPB 64           // nodes per block

typedef __bf16 bf16_t;
typedef __bf16 bf16x4 __attribute__((ext_vector_type(4)));
typedef __bf16 bf16x8 __attribute__((ext_vector_type(8)));
typedef float f32x4 __attribute__((ext_vector_type(4)));

#define TP_NORM    0.022097086912079608f  /* 1/sqrt(16*128) */
#define INV_SQRT_V 0.08838834764831845f   /* 1/sqrt(128) */
#define EPSV       1e-5f
#define SW(r) (((r) & 7) << 4)

static constexpr int    BSW_ELEMS = 128 * 128;                 // bf16 per matrix
static constexpr size_t SSQ_OFF   = 4 * BSW_ELEMS * 2;         // 131072
static constexpr size_t BAR_OFF   = SSQ_OFF + 3 * 1024 * 4;    // ssq: 3x1024 f32
// bar layout (ints): root_arr @0, root_gen @64, grp_arr[g] @128+g*64,
// grp_gen[g] @128+2048+g*64  => 4224 ints

// ---------------------------------------------------------------- K0: weights
// Frag order: flat = ((ot*4+ks)*64 + lane)*8 + j
// value = B[k = ks*32 + (lane>>4)*8 + j][o = ot*16 + (lane&15)]
__global__ __launch_bounds__(256) void k_weights(
    const float* __restrict__ Wt, const float* __restrict__ Wtp1,
    const float* __restrict__ Wv, bf16_t* __restrict__ bsw) {
  int b = blockIdx.x, t = threadIdx.x;
  if (b < 64) {
    int k = 2 * b + (t >> 7);
    int o = t & 127;
    float acc = 0.f;
#pragma unroll
    for (int u = 0; u < 16; ++u) acc += Wt[u] * Wtp1[(u * 128 + k) * 128 + o];
    int ks = k >> 5, hi = (k >> 3) & 3, j = k & 7;
    int l = hi * 16 + (o & 15), ot = o >> 4;
    bsw[((ot * 4 + ks) * 64 + l) * 8 + j] = (bf16_t)(acc * TP_NORM);
  } else {
    int vid = (b - 64) * 256 + t;            // 0..6143
    int mat = 1 + (vid >> 11);
    int idx = vid & 2047;
    int l = idx & 63;
    int o = ((idx >> 8) << 4) + (l & 15);
    int kbase = ((idx >> 6) & 3) * 32 + (l >> 4) * 8;
    bf16x8 o8;
#pragma unroll
    for (int j = 0; j < 8; ++j)
      o8[j] = (bf16_t)(Wv[((mat - 1) * 128 + kbase + j) * 128 + o] * INV_SQRT_V);
    *(bf16x8*)(bsw + (size_t)mat * BSW_ELEMS + (size_t)idx * 8) = o8;
  }
}

// ---- grid barrier: relaxed-only tree; producer ordering via s_waitcnt vmcnt(0)
__device__ __forceinline__ void gridbar(int phase, int* __restrict__ barb) {
  __syncthreads();
  if (threadIdx.x == 0) {
    int g = blockIdx.x >> 4;
    int* grp_arr = barb + 128 + g * 64;
    int* grp_gen = barb + 128 + 2048 + g * 64;
    asm volatile("s_waitcnt vmcnt(0)" ::: "memory");  // ssq atomics complete
    int a = __hip_atomic_fetch_add(grp_arr, 1, __ATOMIC_RELAXED,
                                   __HIP_MEMORY_SCOPE_AGENT);
    if (a == phase * 16 - 1) {                        // last in group
      int ra = __hip_atomic_fetch_add(barb, 1, __ATOMIC_RELAXED,
                                      __HIP_MEMORY_SCOPE_AGENT);
      if (ra == phase * 32 - 1) {                     // last leader
        __hip_atomic_fetch_add(barb + 64, 1, __ATOMIC_RELAXED,
                               __HIP_MEMORY_SCOPE_AGENT);
      } else {
        while (__hip_atomic_load(barb + 64, __ATOMIC_RELAXED,
                                 __HIP_MEMORY_SCOPE_AGENT) < phase)
          __builtin_amdgcn_s_sleep(8);
      }
      __hip_atomic_fetch_add(grp_gen, 1, __ATOMIC_RELAXED,
                             __HIP_MEMORY_SCOPE_AGENT);
    } else {
      while (__hip_atomic_load(grp_gen, __ATOMIC_RELAXED,
                               __HIP_MEMORY_SCOPE_AGENT) < phase)
        __builtin_amdgcn_s_sleep(8);
    }
  }
  __syncthreads();
  asm volatile("" ::: "memory");
}

// ---------------------------------------------------------------- fused kernel
__global__ __launch_bounds__(256, 2) void k_fused(
    const float* __restrict__ feat, const float* __restrict__ times,
    const float* __restrict__ gv, const float* __restrict__ Wr,
    float* __restrict__ out, const bf16_t* __restrict__ bsw,
    float* __restrict__ ssqb, int* __restrict__ barb) {
  __shared__ char  Vt[192 * 256];     // [rl = m*64+nl][chan] bf16, swizzled
  __shared__ char  SG[16 * 784];      // raw interleaved x_v rows (16 nodes)
  __shared__ float tl[64];
  __shared__ float aw[128];
  __shared__ float red[4 * 192];

  int b = blockIdx.x, t = threadIdx.x;
  int n0 = b * NPB;
  if (t < 64) tl[t] = times[n0 + t];

  int w = t >> 6, l = t & 63, lr = l & 15, lq = l >> 4;

  // ---- P1: TP GEMM. 4 chunks x 16 nodes; all 3 planes from one staging.
  {
    bf16x8 cf[2][4];
#pragma unroll
    for (int j = 0; j < 2; ++j)
#pragma unroll
      for (int ks = 0; ks < 4; ++ks)
        cf[j][ks] = *(const bf16x8*)(bsw + (((2 * w + j) * 4 + ks) * 64 + l) * 8);
    for (int c = 0; c < 4; ++c) {
      __syncthreads();   // protect SG from previous chunk's readers
      // stage 16 nodes x 96 float4 (full 384-float x_v span), coalesced
#pragma unroll
      for (int i = 0; i < 6; ++i) {
        int idx = i * 256 + t;          // 0..1535
        int row = idx / 96, c4 = idx - row * 96;
        float4 x = *(const float4*)(feat + (size_t)(n0 + c * 16 + row) * 512 +
                                    128 + c4 * 4);
        bf16x4 b4 = {(bf16_t)x.x, (bf16_t)x.y, (bf16_t)x.z, (bf16_t)x.w};
        *(bf16x4*)(SG + row * 784 + c4 * 8) = b4;
      }
      __syncthreads();
      f32x4 a3[3][2];
#pragma unroll
      for (int m = 0; m < 3; ++m)
#pragma unroll
        for (int j = 0; j < 2; ++j) a3[m][j] = (f32x4){0.f, 0.f, 0.f, 0.f};
#pragma unroll
      for (int ks = 0; ks < 4; ++ks) {
        const char* q = SG + lr * 784 + 192 * ks + 48 * lq;
        bf16x8 r0 = *(const bf16x8*)(q);
        bf16x8 r1 = *(const bf16x8*)(q + 16);
        bf16x8 r2 = *(const bf16x8*)(q + 32);
        bf16x8 xf[3];
#pragma unroll
        for (int m = 0; m < 3; ++m)
#pragma unroll
          for (int j = 0; j < 8; ++j) {
            int s = 3 * j + m;
            xf[m][j] = s < 8 ? r0[s] : (s < 16 ? r1[s - 8] : r2[s - 16]);
          }
#pragma unroll
        for (int m = 0; m < 3; ++m) {
          a3[m][0] = __builtin_amdgcn_mfma_f32_16x16x32_bf16(cf[0][ks], xf[m], a3[m][0], 0, 0, 0);
          a3[m][1] = __builtin_amdgcn_mfma_f32_16x16x32_bf16(cf[1][ks], xf[m], a3[m][1], 0, 0, 0);
        }
      }
      int nl = c * 16 + lr;
      float tv = tl[nl];
#pragma unroll
      for (int m = 0; m < 3; ++m)
#pragma unroll
        for (int j = 0; j < 2; ++j) {
          int rl = m * 64 + nl;
          bf16x4 b4;
#pragma unroll
          for (int i = 0; i < 4; ++i) b4[i] = (bf16_t)(a3[m][j][i] * tv);
          *(bf16x4*)(Vt + rl * 256 + ((((2 * w + j) * 16 + lq * 4) * 2) ^ SW(rl))) = b4;
        }
    }
    __syncthreads();
  }

  // ---- P2..P4: three layer GEMMs in LDS; ssq -> spread atomics -> gridbar
  f32x4 acc[2][12];
  for (int li = 0; li < 3; ++li) {
    if (li >= 1) {
      if (t < 128) {
        float s = 0.f;
#pragma unroll
        for (int q = 0; q < 8; ++q)
          s += __hip_atomic_load(ssqb + (li - 1) * 1024 + q * 128 + t,
                                 __ATOMIC_RELAXED, __HIP_MEMORY_SCOPE_AGENT);
        aw[t] = gv[(li - 1) * 128 + t] * rsqrtf(s * (1.0f / NMf) + EPSV);
      }
      __syncthreads();
    }
    bf16x8 wf[2][4];
#pragma unroll
    for (int j = 0; j < 2; ++j)
#pragma unroll
      for (int ks = 0; ks < 4; ++ks) {
        bf16x8 rw = *(const bf16x8*)(bsw + (size_t)(1 + li) * BSW_ELEMS +
                                     (((2 * w + j) * 4 + ks) * 64 + l) * 8);
        if (li >= 1) {
#pragma unroll
          for (int e = 0; e < 8; ++e)
            rw[e] = (bf16_t)((float)rw[e] * aw[ks * 32 + lq * 8 + e]);
        }
        wf[j][ks] = rw;
      }
#pragma unroll
    for (int j = 0; j < 2; ++j)
#pragma unroll
      for (int g = 0; g < 12; ++g) acc[j][g] = (f32x4){0.f, 0.f, 0.f, 0.f};
#pragma unroll
    for (int g = 0; g < 12; ++g) {
      int row = g * 16 + lr;
#pragma unroll
      for (int ks = 0; ks < 4; ++ks) {
        bf16x8 xf = *(const bf16x8*)(Vt + row * 256 + ((ks * 64 + lq * 16) ^ SW(row)));
        acc[0][g] = __builtin_amdgcn_mfma_f32_16x16x32_bf16(wf[0][ks], xf, acc[0][g], 0, 0, 0);
        acc[1][g] = __builtin_amdgcn_mfma_f32_16x16x32_bf16(wf[1][ks], xf, acc[1][g], 0, 0, 0);
      }
    }
    // per-channel ssq partials (channel o = (2w+j)*16 + lq*4 + i)
    f32x4 s2[2] = {{0.f,0.f,0.f,0.f},{0.f,0.f,0.f,0.f}};
#pragma unroll
    for (int j = 0; j < 2; ++j)
#pragma unroll
      for (int g = 0; g < 12; ++g) s2[j] += acc[j][g] * acc[j][g];
#pragma unroll
    for (int j = 0; j < 2; ++j)
#pragma unroll
      for (int i = 0; i < 4; ++i) {
        float v = s2[j][i];
        v += __shfl_xor(v, 1); v += __shfl_xor(v, 2);
        v += __shfl_xor(v, 4); v += __shfl_xor(v, 8);
        s2[j][i] = v;
      }
    if (lr == 0) {
#pragma unroll
      for (int j = 0; j < 2; ++j)
#pragma unroll
        for (int i = 0; i < 4; ++i)
          atomicAdd(ssqb + li * 1024 + (b & 7) * 128 + (2 * w + j) * 16 + lq * 4 + i,
                    s2[j][i]);
    }
    if (li < 2) {
      __syncthreads();   // all Vt reads done before in-place rewrite
#pragma unroll
      for (int j = 0; j < 2; ++j)
#pragma unroll
        for (int g = 0; g < 12; ++g) {
          int row = g * 16 + lr;
          bf16x4 b4;
#pragma unroll
          for (int i = 0; i < 4; ++i) b4[i] = (bf16_t)(acc[j][g][i]);
          *(bf16x4*)(Vt + row * 256 + ((((2 * w + j) * 16 + lq * 4) * 2) ^ SW(row))) = b4;
        }
    }
    gridbar(li + 1, barb);
  }

  // ---- P5: final dot from layer-3 accumulators
  if (t < 128) {
    float s = 0.f;
#pragma unroll
    for (int q = 0; q < 8; ++q)
      s += __hip_atomic_load(ssqb + 2 * 1024 + q * 128 + t,
                             __ATOMIC_RELAXED, __HIP_MEMORY_SCOPE_AGENT);
    aw[t] = gv[2 * 128 + t] * rsqrtf(s * (1.0f / NMf) + EPSV) * Wr[t] * INV_SQRT_V;
  }
  __syncthreads();
  float part[12];
#pragma unroll
  for (int g = 0; g < 12; ++g) part[g] = 0.f;
#pragma unroll
  for (int j = 0; j < 2; ++j) {
    int ob = (2 * w + j) * 16 + lq * 4;
    float w0 = aw[ob], w1 = aw[ob + 1], w2 = aw[ob + 2], w3v = aw[ob + 3];
#pragma unroll
    for (int g = 0; g < 12; ++g)
      part[g] += acc[j][g][0] * w0 + acc[j][g][1] * w1 +
                 acc[j][g][2] * w2 + acc[j][g][3] * w3v;
  }
#pragma unroll
  for (int g = 0; g < 12; ++g) {
    part[g] += __shfl_xor(part[g], 16);
    part[g] += __shfl_xor(part[g], 32);
  }
  if (lq == 0) {
#pragma unroll
    for (int g = 0; g < 12; ++g) red[w * 192 + g * 16 + lr] = part[g];
  }
  __syncthreads();
  if (t < 192) {
    float s = red[t] + red[192 + t] + red[384 + t] + red[576 + t];
    int m = t >> 6, nl = t & 63;
    out[(size_t)(n0 + nl) * 3 + m] = s;
  }
}

// ---------------------------------------------------------------- launch
extern "C" void kernel_launch(void* const* d_in, const int* in_sizes, int n_in,
                              void* d_out, int out_size, void* d_ws, size_t ws_size,
                              hipStream_t stream) {
  const float* feat  = (const float*)d_in[0];
  const float* times = (const float*)d_in[1];
  const float* Wt    = (const float*)d_in[2];
  const float* Wtp1  = (const float*)d_in[4];   // W_tp0/Ws/gamma_s/beta_s dead
  const float* Wv    = (const float*)d_in[6];
  const float* gv    = (const float*)d_in[9];
  const float* Wr    = (const float*)d_in[10];
  float* out = (float*)d_out;

  bf16_t* bsw  = (bf16_t*)d_ws;
  float*  ssqb = (float*)((char*)d_ws + SSQ_OFF);
  int*    barb = (int*)((char*)d_ws + BAR_OFF);

  // zero ssq accumulators + barrier state (ws is re-poisoned before each launch)
  hipMemsetAsync(ssqb, 0, 3 * 1024 * sizeof(float) + 4224 * sizeof(int), stream);
  k_weights<<<88, 256, 0, stream>>>(Wt, Wtp1, Wv, bsw);
  k_fused<<<NB, 256, 0, stream>>>(feat, times, gv, Wr, out, bsw, ssqb, barb);
}